// Round 7
// baseline (126.315 us; speedup 1.0000x reference)
//
#include <hip/hip_runtime.h>
#include <stdint.h>

// Problem constants
#define T_DIM 2048
#define B_DIM 32
#define DIN   512
#define DOUT  512
#define M_DIM (T_DIM * B_DIM)   // 65536
#define COLS  (B_DIM * DIN)     // 16384
#define COLS4 (COLS / 4)        // 4096

#define ALPHA_F 0.36787944117144233f  // exp(-1)
#define INV_1MA 1.5819767068693265f   // 1/(1-alpha)

#define HALO   8                      // alpha^8 ~ 3.4e-4 on xf -> ~2e-4 on out
#define TSLAB  256                    // t-steps per block
#define NSLABS 8                      // T_DIM / TSLAB

// Fallback-path chunking (fp32 path, only if ws < 512 KB)
#define FCHUNKS  32
#define FCHUNK_T 64
#define FHALO    16

typedef float  floatx4 __attribute__((ext_vector_type(4)));
typedef __bf16 bf16x8  __attribute__((ext_vector_type(8)));

// pack two fp32 -> two bf16 (RNE) in one u32
__device__ __forceinline__ uint32_t pk2(float a, float b) {
  uint32_t ua = __float_as_uint(a); ua += 0x7fffu + ((ua >> 16) & 1u);
  uint32_t ub = __float_as_uint(b); ub += 0x7fffu + ((ub >> 16) & 1u);
  return (ua >> 16) | (ub & 0xffff0000u);
}

__device__ __forceinline__ void gload_lds16(const void* g, void* lds) {
  __builtin_amdgcn_global_load_lds(
      (const __attribute__((address_space(1))) void*)g,
      (__attribute__((address_space(3))) void*)lds,
      16, 0, 0);
}

__device__ __forceinline__ void fma4(float4& c, const float4& v) {
  c.x = fmaf(ALPHA_F, c.x, v.x);
  c.y = fmaf(ALPHA_F, c.y, v.y);
  c.z = fmaf(ALPHA_F, c.z, v.z);
  c.w = fmaf(ALPHA_F, c.w, v.w);
}

// ---------------------------------------------------------------------------
// W fp32 -> bf16 (0.5 MB into ws). grid 16 x 256.
// ---------------------------------------------------------------------------
__global__ void wconv_kernel(const float* __restrict__ W,
                             uint16_t* __restrict__ WB)
{
  const int t = blockIdx.x * 256 + threadIdx.x;   // 0..4095
  const float4* W4 = (const float4*)W;
#pragma unroll
  for (int j = 0; j < 8; ++j) {
    const int b4 = t * 16 + j * 2;
    float4 w0 = W4[b4], w1 = W4[b4 + 1];
    uint4 p;
    p.x = pk2(w0.x, w0.y); p.y = pk2(w0.z, w0.w);
    p.z = pk2(w1.x, w1.y); p.w = pk2(w1.z, w1.w);
    *(uint4*)&WB[t * 64 + j * 8] = p;
  }
}

// ---------------------------------------------------------------------------
// Fused b-slab kernel. Block = (b, t-slab of 256). 256 threads / 4 waves 2x2.
//
// As[128 t][512 k] bf16 (128 KB): per t-subtile (2 of 128 t), thread (k16,th)
//   loads X fp32 (8-halo + 64 t float4), runs the alpha-chain in registers,
//   packs bf16, XOR-swizzled ds_write_b64. X read exactly once (+12.5% halo).
// Bs[2][128 n][64 k] (32 KB): double-buffered global_load_lds from WB
//   (L2-resident), pre-swizzled source; ONE barrier per chunk (stage c+1 ->
//   compute c -> barrier), B latency hidden under MFMA.
// 32 chunks per subtile (4 n-tiles x 8 k-chunks); epilogue at kc==7 writes
//   Y[t,b,n] = acc + s(t)*bias[n],  s(t) = (1-alpha^(t+1))/(1-alpha).
// ---------------------------------------------------------------------------
__launch_bounds__(256, 1)
__global__ void fused_bslab_kernel(const float* __restrict__ X,
                                   const uint16_t* __restrict__ WB,
                                   const float* __restrict__ bias,
                                   float* __restrict__ Y)
{
  __shared__ __align__(16) uint16_t As[128 * 512];      // 128 KB
  __shared__ __align__(16) uint16_t Bs[2][128 * 64];    // 32 KB

  const int bid  = blockIdx.x;
  const int b_   = bid & 31;         // batch index
  const int slab = bid >> 5;         // 0..7
  const int tbase = slab * TSLAB;

  const int tid  = threadIdx.x;
  const int lane = tid & 63;
  const int w    = tid >> 6;
  const int r    = lane & 15;
  const int q    = lane >> 4;
  const int wm   = w >> 1;
  const int wn   = w & 1;

  // A-staging: thread = (k16 column of 16B fp32 / 8B bf16, t-half)
  const int k16 = tid & 127;         // 0..127
  const int th  = tid >> 7;          // 0..1

  // B-staging geometry (global_load_lds): wave w, instr i -> rows w*32+i*8..+7
  const int srow_base = w * 32 + (lane >> 3);
  const int schunk    = lane & 7;

  const float4* X4 = (const float4*)X;
  const float4 zero4 = {0.0f, 0.0f, 0.0f, 0.0f};

  // prologue: stage B chunk 0 into buf 0 (drained by the A-stage barrier)
#pragma unroll
  for (int i = 0; i < 4; ++i) {
    const int row = srow_base + i * 8;
    const int sc = schunk ^ (row & 7);
    gload_lds16(WB + (size_t)row * DIN + sc * 8,
                &Bs[0][(w * 32 + i * 8) * 64]);
  }

  floatx4 acc[4][4];
  float sv[16];

  for (int sub = 0; sub < 2; ++sub) {
    // ---------- A stage: filter 64 owned t (+8 halo) per thread ----------
    const int t0 = tbase + sub * 128 + th * 64;   // first owned t
    float4 va[8], vb[8];
    float4 ca = {0.0f, 0.0f, 0.0f, 0.0f};

    // halo loads into va (t<0 only for slab0/sub0/th0 -> zeros)
#pragma unroll
    for (int j = 0; j < 8; ++j) {
      const int t = t0 - 8 + j;
      va[j] = (t >= 0) ? X4[(size_t)t * 4096 + (size_t)b_ * 128 + k16] : zero4;
    }
    // first main group into vb (issued before halo chain -> overlap)
#pragma unroll
    for (int j = 0; j < 8; ++j)
      vb[j] = X4[(size_t)(t0 + j) * 4096 + (size_t)b_ * 128 + k16];
#pragma unroll
    for (int j = 0; j < 8; ++j) fma4(ca, va[j]);

#pragma unroll
    for (int g = 0; g < 8; ++g) {
      float4* cu = (g & 1) ? va : vb;
      float4* nx = (g & 1) ? vb : va;
      if (g < 7) {
#pragma unroll
        for (int j = 0; j < 8; ++j)
          nx[j] = X4[(size_t)(t0 + (g + 1) * 8 + j) * 4096 + (size_t)b_ * 128 + k16];
      }
#pragma unroll
      for (int j = 0; j < 8; ++j) {
        fma4(ca, cu[j]);
        const int row  = th * 64 + g * 8 + j;          // t-local row 0..127
        const int slot = (k16 >> 1) ^ (row & 7);       // 16B-slot swizzle
        uint2 p;
        p.x = pk2(ca.x, ca.y);
        p.y = pk2(ca.z, ca.w);
        *(uint2*)&As[row * 512 + slot * 8 + (k16 & 1) * 4] = p;
      }
    }

    // s(t) table for this subtile's epilogues
#pragma unroll
    for (int mi = 0; mi < 4; ++mi)
#pragma unroll
      for (int j = 0; j < 4; ++j) {
        const int tg = tbase + sub * 128 + wm * 64 + mi * 16 + q * 4 + j;
        sv[mi * 4 + j] = (1.0f - __expf(-(float)(tg + 1))) * INV_1MA;
      }

    __syncthreads();   // As ready; pending B stage landed; prev compute done

    // ---------- compute: 32 chunks (4 n-tiles x 8 k-chunks) ----------
    for (int c = 0; c < 32; ++c) {
      const int nt = c >> 3;
      const int kc = c & 7;
      const int cb = c & 1;

      // stage next chunk into the other buffer (wraps to chunk 0 for next sub)
      if (!(sub == 1 && c == 31)) {
        const int cn  = (c + 1) & 31;
        const int nnt = cn >> 3;
        const int nkc = cn & 7;
#pragma unroll
        for (int i = 0; i < 4; ++i) {
          const int row = srow_base + i * 8;
          const int sc = schunk ^ (row & 7);
          gload_lds16(WB + (size_t)(nnt * 128 + row) * DIN + nkc * 64 + sc * 8,
                      &Bs[cb ^ 1][(w * 32 + i * 8) * 64]);
        }
      }

      if (kc == 0) {
#pragma unroll
        for (int i = 0; i < 4; ++i)
#pragma unroll
          for (int j2 = 0; j2 < 4; ++j2) {
            floatx4 z = {0.0f, 0.0f, 0.0f, 0.0f};
            acc[i][j2] = z;
          }
      }

#pragma unroll
      for (int kk = 0; kk < 2; ++kk) {
        bf16x8 af[4], bfr[4];
#pragma unroll
        for (int mi = 0; mi < 4; ++mi) {
          const int row  = wm * 64 + mi * 16 + r;
          const int slot = (kc * 8 + kk * 4 + q) ^ (row & 7);
          af[mi] = *(const bf16x8*)&As[row * 512 + slot * 8];
        }
#pragma unroll
        for (int ni = 0; ni < 4; ++ni) {
          const int row = wn * 64 + ni * 16 + r;
          const int cch = (kk * 4 + q) ^ (row & 7);
          bfr[ni] = *(const bf16x8*)&Bs[cb][row * 64 + cch * 8];
        }
#pragma unroll
        for (int mi = 0; mi < 4; ++mi)
#pragma unroll
          for (int ni = 0; ni < 4; ++ni)
            acc[mi][ni] = __builtin_amdgcn_mfma_f32_16x16x32_bf16(
                af[mi], bfr[ni], acc[mi][ni], 0, 0, 0);
      }

      if (kc == 7) {
        // epilogue for n-tile nt
#pragma unroll
        for (int ni = 0; ni < 4; ++ni) {
          const int col = nt * 128 + wn * 64 + ni * 16 + r;
          const float bv = bias[col];
#pragma unroll
          for (int mi = 0; mi < 4; ++mi) {
#pragma unroll
            for (int j = 0; j < 4; ++j) {
              const int tg = tbase + sub * 128 + wm * 64 + mi * 16 + q * 4 + j;
              Y[(size_t)tg * 16384 + (size_t)b_ * 512 + col] =
                  acc[mi][ni][j] + sv[mi * 4 + j] * bv;
            }
          }
        }
      }

      __syncthreads();
    }
  }
}

// ===========================================================================
// FALLBACK PATH (fp32 GEMM + scan; used only if ws < 512 KB)
// ===========================================================================
__launch_bounds__(256, 2)
__global__ void gemm_bias_kernel(const float* __restrict__ X,
                                 const float* __restrict__ W,
                                 const float* __restrict__ bias,
                                 float* __restrict__ Y,
                                 float* __restrict__ halo,
                                 int halo_on)
{
  __shared__ __align__(16) uint16_t As[128 * 64];
  __shared__ __align__(16) uint16_t Bsh[128 * 64];

  const int tid  = threadIdx.x;
  const int lane = tid & 63;
  const int wave = tid >> 6;
  const int wm   = wave >> 1;
  const int wn   = wave & 1;
  const int r    = lane & 15;
  const int q    = lane >> 4;

  const int m0 = blockIdx.y * 128;
  const int n0 = blockIdx.x * 128;

  floatx4 acc[4][4];
#pragma unroll
  for (int i = 0; i < 4; ++i)
#pragma unroll
    for (int j = 0; j < 4; ++j) {
      floatx4 z = {0.0f, 0.0f, 0.0f, 0.0f};
      acc[i][j] = z;
    }

  for (int kt = 0; kt < DIN / 64; ++kt) {
    const int k0 = kt * 64;
#pragma unroll
    for (int j = 0; j < 4; ++j) {
      const int cid = tid + j * 256;
      const int row = cid >> 3;
      const int c   = cid & 7;
      const int slot = (c ^ (row & 7)) << 3;

      const float* ga = &X[(size_t)(m0 + row) * DIN + k0 + c * 8];
      float4 a0 = *(const float4*)ga;
      float4 a1 = *(const float4*)(ga + 4);
      uint4 pa;
      pa.x = pk2(a0.x, a0.y); pa.y = pk2(a0.z, a0.w);
      pa.z = pk2(a1.x, a1.y); pa.w = pk2(a1.z, a1.w);
      *(uint4*)&As[row * 64 + slot] = pa;

      const float* gb = &W[(size_t)(n0 + row) * DIN + k0 + c * 8];
      float4 b0 = *(const float4*)gb;
      float4 b1 = *(const float4*)(gb + 4);
      uint4 pb;
      pb.x = pk2(b0.x, b0.y); pb.y = pk2(b0.z, b0.w);
      pb.z = pk2(b1.x, b1.y); pb.w = pk2(b1.z, b1.w);
      *(uint4*)&Bsh[row * 64 + slot] = pb;
    }
    __syncthreads();

#pragma unroll
    for (int kk = 0; kk < 2; ++kk) {
      bf16x8 af[4], bfr[4];
#pragma unroll
      for (int mi = 0; mi < 4; ++mi) {
        const int row = wm * 64 + mi * 16 + r;
        const int c   = (kk * 4 + q) ^ (row & 7);
        af[mi] = *(const bf16x8*)&As[row * 64 + (c << 3)];
      }
#pragma unroll
      for (int ni = 0; ni < 4; ++ni) {
        const int row = wn * 64 + ni * 16 + r;
        const int c   = (kk * 4 + q) ^ (row & 7);
        bfr[ni] = *(const bf16x8*)&Bsh[row * 64 + (c << 3)];
      }
#pragma unroll
      for (int mi = 0; mi < 4; ++mi)
#pragma unroll
        for (int ni = 0; ni < 4; ++ni)
          acc[mi][ni] = __builtin_amdgcn_mfma_f32_16x16x32_bf16(
              af[mi], bfr[ni], acc[mi][ni], 0, 0, 0);
    }
    __syncthreads();
  }

#pragma unroll
  for (int ni = 0; ni < 4; ++ni) {
    const int col = n0 + wn * 64 + ni * 16 + r;
    const float bv = bias[col];
#pragma unroll
    for (int mi = 0; mi < 4; ++mi) {
      const int rowm = m0 + wm * 64 + mi * 16 + q * 4;
      const int t = rowm >> 5;
      const int b = rowm & 31;
      const int tloc = t & (FCHUNK_T - 1);
      const bool hw = halo_on && (tloc >= FCHUNK_T - FHALO) && (t < T_DIM - FCHUNK_T);
      const size_t hbase = hw
          ? ((size_t)(((t >> 6) + 1) * FHALO + (tloc - (FCHUNK_T - FHALO))) * COLS)
          : 0;
#pragma unroll
      for (int j = 0; j < 4; ++j) {
        const float v = acc[mi][ni][j] + bv;
        Y[(size_t)(rowm + j) * DOUT + col] = v;
        if (hw) halo[hbase + (size_t)(b + j) * DOUT + col] = v;
      }
    }
  }
}

__global__ void scan_kernel(float* __restrict__ Y,
                            const float* __restrict__ halo,
                            int chunk_len)
{
  const int col4 = blockIdx.x * blockDim.x + threadIdx.x;
  const int c = blockIdx.y;

  float4* Y4 = (float4*)Y;
  const float4* H4 = (const float4*)halo;

  float4 carry = {0.0f, 0.0f, 0.0f, 0.0f};
  if (c > 0) {
#pragma unroll
    for (int h = 0; h < FHALO; ++h) {
      float4 v = H4[(size_t)(c * FHALO + h) * COLS4 + col4];
      fma4(carry, v);
    }
  }

  size_t idx = (size_t)c * chunk_len * COLS4 + col4;
  float4 ynext = Y4[idx];
  for (int t = 0; t < chunk_len; ++t) {
    float4 y = ynext;
    if (t + 1 < chunk_len) ynext = Y4[idx + COLS4];
    fma4(carry, y);
    Y4[idx] = carry;
    idx += COLS4;
  }
}

// ---------------------------------------------------------------------------
extern "C" void kernel_launch(void* const* d_in, const int* in_sizes, int n_in,
                              void* d_out, int out_size, void* d_ws, size_t ws_size,
                              hipStream_t stream)
{
  const float* X    = (const float*)d_in[0];  // [T, B, DIN]
  const float* W    = (const float*)d_in[1];  // [DOUT, DIN]
  const float* bias = (const float*)d_in[2];  // [DOUT]
  float* Y = (float*)d_out;                   // [T, B, DOUT]

  const size_t need_wb = (size_t)DOUT * DIN * 2;  // 512 KiB

  if (ws_size >= need_wb) {
    uint16_t* WB = (uint16_t*)d_ws;
    wconv_kernel<<<16, 256, 0, stream>>>(W, WB);
    fused_bslab_kernel<<<B_DIM * NSLABS, 256, 0, stream>>>(X, WB, bias, Y);
  } else {
    float* halo = (float*)d_ws;
    const size_t halo_need = (size_t)FCHUNKS * FHALO * COLS * sizeof(float);
    const int halo_on = (ws_size >= halo_need) ? 1 : 0;

    dim3 g1(DOUT / 128, M_DIM / 128);
    gemm_bias_kernel<<<g1, 256, 0, stream>>>(X, W, bias, Y, halo, halo_on);

    const int n_chunks = halo_on ? FCHUNKS : 1;
    dim3 g2(COLS4 / 256, n_chunks);
    scan_kernel<<<g2, 256, 0, stream>>>(Y, halo, T_DIM / n_chunks);
  }
}

// Round 8
// 106.240 us; speedup vs baseline: 1.1890x; 1.1890x over previous
//
#include <hip/hip_runtime.h>
#include <stdint.h>

// Problem constants
#define T_DIM 2048
#define B_DIM 32
#define DIN   512
#define DOUT  512
#define M_DIM (T_DIM * B_DIM)   // 65536
#define COLS  (B_DIM * DIN)     // 16384
#define COLS4 (COLS / 4)        // 4096

#define ALPHA_F 0.36787944117144233f  // exp(-1)
#define INV_1MA 1.5819767068693265f   // 1/(1-alpha)

// Filter chunking: 64 chunks of 32 timesteps, 8-step halo (alpha^8 ~ 3.4e-4
// on xf -> ~2e-4 on out after the 512-dot; far below bf16-GEMM floor 0.0156)
#define CHUNKS   64
#define CHUNK_T  32
#define HALO     8

// Fallback-path chunking (fp32 path, only if ws < 64.5 MB)
#define FCHUNKS  32
#define FCHUNK_T 64
#define FHALO    16

typedef float  floatx4 __attribute__((ext_vector_type(4)));
typedef __bf16 bf16x8  __attribute__((ext_vector_type(8)));

// pack two fp32 -> two bf16 (RNE) in one u32
__device__ __forceinline__ uint32_t pk2(float a, float b) {
  uint32_t ua = __float_as_uint(a); ua += 0x7fffu + ((ua >> 16) & 1u);
  uint32_t ub = __float_as_uint(b); ub += 0x7fffu + ((ub >> 16) & 1u);
  return (ua >> 16) | (ub & 0xffff0000u);
}

__device__ __forceinline__ void gload_lds16(const void* g, void* lds) {
  __builtin_amdgcn_global_load_lds(
      (const __attribute__((address_space(1))) void*)g,
      (__attribute__((address_space(3))) void*)lds,
      16, 0, 0);
}

__device__ __forceinline__ void fma4(float4& c, const float4& v) {
  c.x = fmaf(ALPHA_F, c.x, v.x);
  c.y = fmaf(ALPHA_F, c.y, v.y);
  c.z = fmaf(ALPHA_F, c.z, v.z);
  c.w = fmaf(ALPHA_F, c.w, v.w);
}

// ---------------------------------------------------------------------------
// W fp32 -> bf16 (0.5 MB into ws). grid 16 x 256.
// ---------------------------------------------------------------------------
__global__ void wconv_kernel(const float* __restrict__ W,
                             uint16_t* __restrict__ WB)
{
  const int t = blockIdx.x * 256 + threadIdx.x;   // 0..4095
  const float4* W4 = (const float4*)W;
#pragma unroll
  for (int j = 0; j < 8; ++j) {
    const int b4 = t * 16 + j * 2;
    float4 w0 = W4[b4], w1 = W4[b4 + 1];
    uint4 p;
    p.x = pk2(w0.x, w0.y); p.y = pk2(w0.z, w0.w);
    p.z = pk2(w1.x, w1.y); p.w = pk2(w1.z, w1.w);
    *(uint4*)&WB[t * 64 + j * 8] = p;
  }
}

// ---------------------------------------------------------------------------
// Kernel 1: chunked exponential filter on X (fp32 -> bf16 XF).
// Rolling depth-4 pipeline: consume step s, immediately issue s+4.
// ~100% load-issue duty cycle, ~40 VGPR -> max wave residency.
// Thread owns one col4 (16B/t). grid (16, CHUNKS) x 256.
// ---------------------------------------------------------------------------
template<bool HAS_HALO>
__device__ __forceinline__ void filter_chunk(const float4* __restrict__ X4,
                                             uint16_t* __restrict__ XF,
                                             size_t base)
{
  constexpr int NSTEP = HAS_HALO ? (CHUNK_T + HALO) : CHUNK_T;
  const size_t b0 = HAS_HALO ? (base - (size_t)HALO * COLS4) : base;

  float4 ring[4];
  float4 carry = {0.0f, 0.0f, 0.0f, 0.0f};

#pragma unroll
  for (int j = 0; j < 4; ++j) ring[j] = X4[b0 + (size_t)j * COLS4];

#pragma unroll
  for (int s = 0; s < NSTEP; ++s) {
    float4 v = ring[s & 3];
    if (s + 4 < NSTEP) ring[s & 3] = X4[b0 + (size_t)(s + 4) * COLS4];
    fma4(carry, v);
    const int t = HAS_HALO ? (s - HALO) : s;
    if (t >= 0) {
      uint2 p;
      p.x = pk2(carry.x, carry.y);
      p.y = pk2(carry.z, carry.w);
      *(uint2*)&XF[(base + (size_t)t * COLS4) * 4] = p;
    }
  }
}

__global__ void filter_x_kernel(const float* __restrict__ X,
                                uint16_t* __restrict__ XF)
{
  const int col4 = blockIdx.x * 256 + threadIdx.x;  // 0..4095
  const int c = blockIdx.y;
  const float4* X4 = (const float4*)X;
  const size_t base = (size_t)c * CHUNK_T * COLS4 + col4;

  if (c > 0) filter_chunk<true>(X4, XF, base);
  else       filter_chunk<false>(X4, XF, base);
}

// ---------------------------------------------------------------------------
// Kernel 2: bf16 GEMM (m97 structure): Y[m,n] = XF[m,:]·WB[n,:] + s(t)·bias[n]
// BM=BN=128, BK=64; 256 thr / 4 waves (2x2), 64x64 per wave.
// global_load_lds width16 with PRE-SWIZZLED global source (linear LDS dest),
// XOR-swizzled ds_read_b128 (conflict-free), chunked XCD swizzle.
// ---------------------------------------------------------------------------
__launch_bounds__(256, 4)
__global__ void gemm_bf16_kernel(const uint16_t* __restrict__ XF,
                                 const uint16_t* __restrict__ WB,
                                 const float* __restrict__ bias,
                                 float* __restrict__ Y)
{
  __shared__ __align__(16) uint16_t As[128 * 64];
  __shared__ __align__(16) uint16_t Bs[128 * 64];

  const int bid = blockIdx.x;
  const int lg = (bid & 7) * 256 + (bid >> 3);
  const int n0 = (lg & 3) * 128;
  const int m0 = (lg >> 2) * 128;

  const int tid  = threadIdx.x;
  const int lane = tid & 63;
  const int w    = tid >> 6;
  const int r    = lane & 15;
  const int q    = lane >> 4;
  const int wm   = w >> 1;
  const int wn   = w & 1;

  const int srow_base = w * 32 + (lane >> 3);
  const int schunk    = lane & 7;

  floatx4 acc[4][4];
#pragma unroll
  for (int i = 0; i < 4; ++i)
#pragma unroll
    for (int j = 0; j < 4; ++j) {
      floatx4 z = {0.0f, 0.0f, 0.0f, 0.0f};
      acc[i][j] = z;
    }

  for (int kt = 0; kt < DIN / 64; ++kt) {
    const int k0 = kt * 64;
#pragma unroll
    for (int i = 0; i < 4; ++i) {
      const int row = srow_base + i * 8;
      const int sc = schunk ^ (row & 7);
      gload_lds16(XF + (size_t)(m0 + row) * DIN + k0 + sc * 8,
                  &As[(w * 32 + i * 8) * 64]);
      gload_lds16(WB + (size_t)(n0 + row) * DIN + k0 + sc * 8,
                  &Bs[(w * 32 + i * 8) * 64]);
    }
    __syncthreads();

#pragma unroll
    for (int kk = 0; kk < 2; ++kk) {
      bf16x8 af[4], bfr[4];
#pragma unroll
      for (int mi = 0; mi < 4; ++mi) {
        const int row = wm * 64 + mi * 16 + r;
        const int cch = (kk * 4 + q) ^ (row & 7);
        af[mi] = *(const bf16x8*)&As[row * 64 + (cch << 3)];
      }
#pragma unroll
      for (int ni = 0; ni < 4; ++ni) {
        const int row = wn * 64 + ni * 16 + r;
        const int cch = (kk * 4 + q) ^ (row & 7);
        bfr[ni] = *(const bf16x8*)&Bs[row * 64 + (cch << 3)];
      }
#pragma unroll
      for (int mi = 0; mi < 4; ++mi)
#pragma unroll
        for (int ni = 0; ni < 4; ++ni)
          acc[mi][ni] = __builtin_amdgcn_mfma_f32_16x16x32_bf16(
              af[mi], bfr[ni], acc[mi][ni], 0, 0, 0);
    }
    __syncthreads();
  }

#pragma unroll
  for (int mi = 0; mi < 4; ++mi) {
    const int rowb = m0 + wm * 64 + mi * 16;
    const int t = rowb >> 5;
    const float s = (1.0f - __expf(-(float)(t + 1))) * INV_1MA;
#pragma unroll
    for (int ni = 0; ni < 4; ++ni) {
      const int col = n0 + wn * 64 + ni * 16 + r;
      const float sb = s * bias[col];
#pragma unroll
      for (int j = 0; j < 4; ++j)
        Y[(size_t)(rowb + q * 4 + j) * DOUT + col] = acc[mi][ni][j] + sb;
    }
  }
}

// ===========================================================================
// FALLBACK PATH (fp32 GEMM + scan; used only if ws < 64.5 MB)
// ===========================================================================
__launch_bounds__(256, 2)
__global__ void gemm_bias_kernel(const float* __restrict__ X,
                                 const float* __restrict__ W,
                                 const float* __restrict__ bias,
                                 float* __restrict__ Y,
                                 float* __restrict__ halo,
                                 int halo_on)
{
  __shared__ __align__(16) uint16_t As[128 * 64];
  __shared__ __align__(16) uint16_t Bsh[128 * 64];

  const int tid  = threadIdx.x;
  const int lane = tid & 63;
  const int wave = tid >> 6;
  const int wm   = wave >> 1;
  const int wn   = wave & 1;
  const int r    = lane & 15;
  const int q    = lane >> 4;

  const int m0 = blockIdx.y * 128;
  const int n0 = blockIdx.x * 128;

  floatx4 acc[4][4];
#pragma unroll
  for (int i = 0; i < 4; ++i)
#pragma unroll
    for (int j = 0; j < 4; ++j) {
      floatx4 z = {0.0f, 0.0f, 0.0f, 0.0f};
      acc[i][j] = z;
    }

  for (int kt = 0; kt < DIN / 64; ++kt) {
    const int k0 = kt * 64;
#pragma unroll
    for (int j = 0; j < 4; ++j) {
      const int cid = tid + j * 256;
      const int row = cid >> 3;
      const int c   = cid & 7;
      const int slot = (c ^ (row & 7)) << 3;

      const float* ga = &X[(size_t)(m0 + row) * DIN + k0 + c * 8];
      float4 a0 = *(const float4*)ga;
      float4 a1 = *(const float4*)(ga + 4);
      uint4 pa;
      pa.x = pk2(a0.x, a0.y); pa.y = pk2(a0.z, a0.w);
      pa.z = pk2(a1.x, a1.y); pa.w = pk2(a1.z, a1.w);
      *(uint4*)&As[row * 64 + slot] = pa;

      const float* gb = &W[(size_t)(n0 + row) * DIN + k0 + c * 8];
      float4 b0 = *(const float4*)gb;
      float4 b1 = *(const float4*)(gb + 4);
      uint4 pb;
      pb.x = pk2(b0.x, b0.y); pb.y = pk2(b0.z, b0.w);
      pb.z = pk2(b1.x, b1.y); pb.w = pk2(b1.z, b1.w);
      *(uint4*)&Bsh[row * 64 + slot] = pb;
    }
    __syncthreads();

#pragma unroll
    for (int kk = 0; kk < 2; ++kk) {
      bf16x8 af[4], bfr[4];
#pragma unroll
      for (int mi = 0; mi < 4; ++mi) {
        const int row = wm * 64 + mi * 16 + r;
        const int c   = (kk * 4 + q) ^ (row & 7);
        af[mi] = *(const bf16x8*)&As[row * 64 + (c << 3)];
      }
#pragma unroll
      for (int ni = 0; ni < 4; ++ni) {
        const int row = wn * 64 + ni * 16 + r;
        const int c   = (kk * 4 + q) ^ (row & 7);
        bfr[ni] = *(const bf16x8*)&Bsh[row * 64 + (c << 3)];
      }
#pragma unroll
      for (int mi = 0; mi < 4; ++mi)
#pragma unroll
        for (int ni = 0; ni < 4; ++ni)
          acc[mi][ni] = __builtin_amdgcn_mfma_f32_16x16x32_bf16(
              af[mi], bfr[ni], acc[mi][ni], 0, 0, 0);
    }
    __syncthreads();
  }

#pragma unroll
  for (int ni = 0; ni < 4; ++ni) {
    const int col = n0 + wn * 64 + ni * 16 + r;
    const float bv = bias[col];
#pragma unroll
    for (int mi = 0; mi < 4; ++mi) {
      const int rowm = m0 + wm * 64 + mi * 16 + q * 4;
      const int t = rowm >> 5;
      const int b = rowm & 31;
      const int tloc = t & (FCHUNK_T - 1);
      const bool hw = halo_on && (tloc >= FCHUNK_T - FHALO) && (t < T_DIM - FCHUNK_T);
      const size_t hbase = hw
          ? ((size_t)(((t >> 6) + 1) * FHALO + (tloc - (FCHUNK_T - FHALO))) * COLS)
          : 0;
#pragma unroll
      for (int j = 0; j < 4; ++j) {
        const float v = acc[mi][ni][j] + bv;
        Y[(size_t)(rowm + j) * DOUT + col] = v;
        if (hw) halo[hbase + (size_t)(b + j) * DOUT + col] = v;
      }
    }
  }
}

__global__ void scan_kernel(float* __restrict__ Y,
                            const float* __restrict__ halo,
                            int chunk_len)
{
  const int col4 = blockIdx.x * blockDim.x + threadIdx.x;
  const int c = blockIdx.y;

  float4* Y4 = (float4*)Y;
  const float4* H4 = (const float4*)halo;

  float4 carry = {0.0f, 0.0f, 0.0f, 0.0f};
  if (c > 0) {
#pragma unroll
    for (int h = 0; h < FHALO; ++h) {
      float4 v = H4[(size_t)(c * FHALO + h) * COLS4 + col4];
      fma4(carry, v);
    }
  }

  size_t idx = (size_t)c * chunk_len * COLS4 + col4;
  float4 ynext = Y4[idx];
  for (int t = 0; t < chunk_len; ++t) {
    float4 y = ynext;
    if (t + 1 < chunk_len) ynext = Y4[idx + COLS4];
    fma4(carry, y);
    Y4[idx] = carry;
    idx += COLS4;
  }
}

// ---------------------------------------------------------------------------
extern "C" void kernel_launch(void* const* d_in, const int* in_sizes, int n_in,
                              void* d_out, int out_size, void* d_ws, size_t ws_size,
                              hipStream_t stream)
{
  const float* X    = (const float*)d_in[0];  // [T, B, DIN]
  const float* W    = (const float*)d_in[1];  // [DOUT, DIN]
  const float* bias = (const float*)d_in[2];  // [DOUT]
  float* Y = (float*)d_out;                   // [T, B, DOUT]

  const size_t need_new = (size_t)M_DIM * DIN * 2 + (size_t)DOUT * DIN * 2; // 64.5 MiB

  if (ws_size >= need_new) {
    uint16_t* XF = (uint16_t*)d_ws;
    uint16_t* WB = XF + (size_t)M_DIM * DIN;

    wconv_kernel<<<16, 256, 0, stream>>>(W, WB);
    dim3 gf(16, CHUNKS);
    filter_x_kernel<<<gf, 256, 0, stream>>>(X, XF);
    gemm_bf16_kernel<<<2048, 256, 0, stream>>>(XF, WB, bias, Y);
  } else {
    float* halo = (float*)d_ws;
    const size_t halo_need = (size_t)FCHUNKS * FHALO * COLS * sizeof(float);
    const int halo_on = (ws_size >= halo_need) ? 1 : 0;

    dim3 g1(DOUT / 128, M_DIM / 128);
    gemm_bias_kernel<<<g1, 256, 0, stream>>>(X, W, bias, Y, halo, halo_on);

    const int n_chunks = halo_on ? FCHUNKS : 1;
    dim3 g2(COLS4 / 256, n_chunks);
    scan_kernel<<<g2, 256, 0, stream>>>(Y, halo, T_DIM / n_chunks);
  }
}

// Round 9
// 91.385 us; speedup vs baseline: 1.3822x; 1.1626x over previous
//
#include <hip/hip_runtime.h>
#include <stdint.h>

// Problem constants
#define T_DIM 2048
#define B_DIM 32
#define DIN   512
#define DOUT  512
#define M_DIM (T_DIM * B_DIM)   // 65536
#define COLS  (B_DIM * DIN)     // 16384
#define COLS4 (COLS / 4)        // 4096

#define ALPHA_F 0.36787944117144233f  // exp(-1)
#define INV_1MA 1.5819767068693265f   // 1/(1-alpha)

// LDS-staged filter tiling: per block 32 output t x 64 float4 cols, 8-t halo
#define FT_T    32
#define FT_HALO 8
#define FT_ROWS (FT_T + FT_HALO)   // 40 staged rows
#define FT_C4   64                 // float4 columns per block (1KB/row)

// Fallback-path chunking (fp32 path, only if ws < 64.5 MB)
#define FCHUNKS  32
#define FCHUNK_T 64
#define FHALO    16

typedef float  floatx4 __attribute__((ext_vector_type(4)));
typedef __bf16 bf16x8  __attribute__((ext_vector_type(8)));

// pack two fp32 -> two bf16 (RNE) in one u32
__device__ __forceinline__ uint32_t pk2(float a, float b) {
  uint32_t ua = __float_as_uint(a); ua += 0x7fffu + ((ua >> 16) & 1u);
  uint32_t ub = __float_as_uint(b); ub += 0x7fffu + ((ub >> 16) & 1u);
  return (ua >> 16) | (ub & 0xffff0000u);
}

__device__ __forceinline__ void gload_lds16(const void* g, void* lds) {
  __builtin_amdgcn_global_load_lds(
      (const __attribute__((address_space(1))) void*)g,
      (__attribute__((address_space(3))) void*)lds,
      16, 0, 0);
}

__device__ __forceinline__ void fma4(float4& c, const float4& v) {
  c.x = fmaf(ALPHA_F, c.x, v.x);
  c.y = fmaf(ALPHA_F, c.y, v.y);
  c.z = fmaf(ALPHA_F, c.z, v.z);
  c.w = fmaf(ALPHA_F, c.w, v.w);
}

// ---------------------------------------------------------------------------
// W fp32 -> bf16 (0.5 MB into ws). grid 16 x 256.
// ---------------------------------------------------------------------------
__global__ void wconv_kernel(const float* __restrict__ W,
                             uint16_t* __restrict__ WB)
{
  const int t = blockIdx.x * 256 + threadIdx.x;   // 0..4095
  const float4* W4 = (const float4*)W;
#pragma unroll
  for (int j = 0; j < 8; ++j) {
    const int b4 = t * 16 + j * 2;
    float4 w0 = W4[b4], w1 = W4[b4 + 1];
    uint4 p;
    p.x = pk2(w0.x, w0.y); p.y = pk2(w0.z, w0.w);
    p.z = pk2(w1.x, w1.y); p.w = pk2(w1.z, w1.w);
    *(uint4*)&WB[t * 64 + j * 8] = p;
  }
}

// ---------------------------------------------------------------------------
// Kernel 1: LDS-staged exponential filter (fp32 X -> bf16 XF).
// Block tile: rows t0-8..t0+31 x 64 float4 (40 KB LDS), staged with
// global_load_lds (1KB contiguous per row, 10 instrs/wave, no VGPR cost).
// Compute: thread (col4=lane, seg=wave) runs 8-halo + 8-output alpha-chain
// out of LDS (consecutive-lane ds_read_b128, conflict-free). Every output
// has >=9 taps: truncation ~2e-4 on xf, ~7e-5 on out -> invisible.
// grid (COLS4/FT_C4, T_DIM/FT_T) = (64, 64) x 256.
// ---------------------------------------------------------------------------
__global__ void filter_x_kernel(const float* __restrict__ X,
                                uint16_t* __restrict__ XF)
{
  __shared__ __align__(16) float lds[FT_ROWS * FT_C4 * 4];   // 40 KB

  const int ct = blockIdx.x;          // col-tile
  const int tt = blockIdx.y;          // t-tile
  const int tid  = threadIdx.x;
  const int lane = tid & 63;
  const int w    = tid >> 6;
  const int t0   = tt * FT_T;
  const size_t gc4 = (size_t)ct * FT_C4;   // base col in float4 units

  float4* L4 = (float4*)lds;

  // ---- stage: rows r=0..39 hold t = t0-8+r ----
  if (tt == 0) {
    // zero halo rows 0..7 (t<0)
    const float4 z = {0.0f, 0.0f, 0.0f, 0.0f};
#pragma unroll
    for (int i = 0; i < 2; ++i)
      L4[tid + i * 256] = z;
    // rows 8..39 -> t = 0..31, 8 instrs per wave
#pragma unroll
    for (int i = 0; i < 8; ++i) {
      const int row = 8 + w + i * 4;
      gload_lds16(X + ((size_t)(t0 + row - 8) * COLS4 + gc4 + lane) * 4,
                  &L4[row * FT_C4]);
    }
  } else {
#pragma unroll
    for (int i = 0; i < 10; ++i) {
      const int row = w + i * 4;
      gload_lds16(X + ((size_t)(t0 - 8 + row) * COLS4 + gc4 + lane) * 4,
                  &L4[row * FT_C4]);
    }
  }
  __syncthreads();

  // ---- compute: wave = seg (8 output t), lane = col4 ----
  const int seg = w;                  // 0..3
  float4 carry = {0.0f, 0.0f, 0.0f, 0.0f};
#pragma unroll
  for (int j = 0; j < 16; ++j) {
    const int r = seg * 8 + j;        // staged row
    float4 v = L4[r * FT_C4 + lane];
    fma4(carry, v);
    if (j >= 8) {
      const int o = seg * 8 + j - 8;  // local output t
      uint2 p;
      p.x = pk2(carry.x, carry.y);
      p.y = pk2(carry.z, carry.w);
      *(uint2*)&XF[((size_t)(t0 + o) * COLS4 + gc4 + lane) * 4] = p;
    }
  }
}

// ---------------------------------------------------------------------------
// Kernel 2: bf16 GEMM (m97 structure): Y[m,n] = XF[m,:]·WB[n,:] + s(t)·bias[n]
// BM=BN=128, BK=64; 256 thr / 4 waves (2x2), 64x64 per wave.
// global_load_lds width16 with PRE-SWIZZLED global source (linear LDS dest),
// XOR-swizzled ds_read_b128 (conflict-free), chunked XCD swizzle.
// ---------------------------------------------------------------------------
__launch_bounds__(256, 4)
__global__ void gemm_bf16_kernel(const uint16_t* __restrict__ XF,
                                 const uint16_t* __restrict__ WB,
                                 const float* __restrict__ bias,
                                 float* __restrict__ Y)
{
  __shared__ __align__(16) uint16_t As[128 * 64];
  __shared__ __align__(16) uint16_t Bs[128 * 64];

  const int bid = blockIdx.x;
  const int lg = (bid & 7) * 256 + (bid >> 3);
  const int n0 = (lg & 3) * 128;
  const int m0 = (lg >> 2) * 128;

  const int tid  = threadIdx.x;
  const int lane = tid & 63;
  const int w    = tid >> 6;
  const int r    = lane & 15;
  const int q    = lane >> 4;
  const int wm   = w >> 1;
  const int wn   = w & 1;

  const int srow_base = w * 32 + (lane >> 3);
  const int schunk    = lane & 7;

  floatx4 acc[4][4];
#pragma unroll
  for (int i = 0; i < 4; ++i)
#pragma unroll
    for (int j = 0; j < 4; ++j) {
      floatx4 z = {0.0f, 0.0f, 0.0f, 0.0f};
      acc[i][j] = z;
    }

  for (int kt = 0; kt < DIN / 64; ++kt) {
    const int k0 = kt * 64;
#pragma unroll
    for (int i = 0; i < 4; ++i) {
      const int row = srow_base + i * 8;
      const int sc = schunk ^ (row & 7);
      gload_lds16(XF + (size_t)(m0 + row) * DIN + k0 + sc * 8,
                  &As[(w * 32 + i * 8) * 64]);
      gload_lds16(WB + (size_t)(n0 + row) * DIN + k0 + sc * 8,
                  &Bs[(w * 32 + i * 8) * 64]);
    }
    __syncthreads();

#pragma unroll
    for (int kk = 0; kk < 2; ++kk) {
      bf16x8 af[4], bfr[4];
#pragma unroll
      for (int mi = 0; mi < 4; ++mi) {
        const int row = wm * 64 + mi * 16 + r;
        const int cch = (kk * 4 + q) ^ (row & 7);
        af[mi] = *(const bf16x8*)&As[row * 64 + (cch << 3)];
      }
#pragma unroll
      for (int ni = 0; ni < 4; ++ni) {
        const int row = wn * 64 + ni * 16 + r;
        const int cch = (kk * 4 + q) ^ (row & 7);
        bfr[ni] = *(const bf16x8*)&Bs[row * 64 + (cch << 3)];
      }
#pragma unroll
      for (int mi = 0; mi < 4; ++mi)
#pragma unroll
        for (int ni = 0; ni < 4; ++ni)
          acc[mi][ni] = __builtin_amdgcn_mfma_f32_16x16x32_bf16(
              af[mi], bfr[ni], acc[mi][ni], 0, 0, 0);
    }
    __syncthreads();
  }

#pragma unroll
  for (int mi = 0; mi < 4; ++mi) {
    const int rowb = m0 + wm * 64 + mi * 16;
    const int t = rowb >> 5;
    const float s = (1.0f - __expf(-(float)(t + 1))) * INV_1MA;
#pragma unroll
    for (int ni = 0; ni < 4; ++ni) {
      const int col = n0 + wn * 64 + ni * 16 + r;
      const float sb = s * bias[col];
#pragma unroll
      for (int j = 0; j < 4; ++j)
        Y[(size_t)(rowb + q * 4 + j) * DOUT + col] = acc[mi][ni][j] + sb;
    }
  }
}

// ===========================================================================
// FALLBACK PATH (fp32 GEMM + scan; used only if ws < 64.5 MB)
// ===========================================================================
__launch_bounds__(256, 2)
__global__ void gemm_bias_kernel(const float* __restrict__ X,
                                 const float* __restrict__ W,
                                 const float* __restrict__ bias,
                                 float* __restrict__ Y,
                                 float* __restrict__ halo,
                                 int halo_on)
{
  __shared__ __align__(16) uint16_t As[128 * 64];
  __shared__ __align__(16) uint16_t Bsh[128 * 64];

  const int tid  = threadIdx.x;
  const int lane = tid & 63;
  const int wave = tid >> 6;
  const int wm   = wave >> 1;
  const int wn   = wave & 1;
  const int r    = lane & 15;
  const int q    = lane >> 4;

  const int m0 = blockIdx.y * 128;
  const int n0 = blockIdx.x * 128;

  floatx4 acc[4][4];
#pragma unroll
  for (int i = 0; i < 4; ++i)
#pragma unroll
    for (int j = 0; j < 4; ++j) {
      floatx4 z = {0.0f, 0.0f, 0.0f, 0.0f};
      acc[i][j] = z;
    }

  for (int kt = 0; kt < DIN / 64; ++kt) {
    const int k0 = kt * 64;
#pragma unroll
    for (int j = 0; j < 4; ++j) {
      const int cid = tid + j * 256;
      const int row = cid >> 3;
      const int c   = cid & 7;
      const int slot = (c ^ (row & 7)) << 3;

      const float* ga = &X[(size_t)(m0 + row) * DIN + k0 + c * 8];
      float4 a0 = *(const float4*)ga;
      float4 a1 = *(const float4*)(ga + 4);
      uint4 pa;
      pa.x = pk2(a0.x, a0.y); pa.y = pk2(a0.z, a0.w);
      pa.z = pk2(a1.x, a1.y); pa.w = pk2(a1.z, a1.w);
      *(uint4*)&As[row * 64 + slot] = pa;

      const float* gb = &W[(size_t)(n0 + row) * DIN + k0 + c * 8];
      float4 b0 = *(const float4*)gb;
      float4 b1 = *(const float4*)(gb + 4);
      uint4 pb;
      pb.x = pk2(b0.x, b0.y); pb.y = pk2(b0.z, b0.w);
      pb.z = pk2(b1.x, b1.y); pb.w = pk2(b1.z, b1.w);
      *(uint4*)&Bsh[row * 64 + slot] = pb;
    }
    __syncthreads();

#pragma unroll
    for (int kk = 0; kk < 2; ++kk) {
      bf16x8 af[4], bfr[4];
#pragma unroll
      for (int mi = 0; mi < 4; ++mi) {
        const int row = wm * 64 + mi * 16 + r;
        const int c   = (kk * 4 + q) ^ (row & 7);
        af[mi] = *(const bf16x8*)&As[row * 64 + (c << 3)];
      }
#pragma unroll
      for (int ni = 0; ni < 4; ++ni) {
        const int row = wn * 64 + ni * 16 + r;
        const int c   = (kk * 4 + q) ^ (row & 7);
        bfr[ni] = *(const bf16x8*)&Bsh[row * 64 + (c << 3)];
      }
#pragma unroll
      for (int mi = 0; mi < 4; ++mi)
#pragma unroll
        for (int ni = 0; ni < 4; ++ni)
          acc[mi][ni] = __builtin_amdgcn_mfma_f32_16x16x32_bf16(
              af[mi], bfr[ni], acc[mi][ni], 0, 0, 0);
    }
    __syncthreads();
  }

#pragma unroll
  for (int ni = 0; ni < 4; ++ni) {
    const int col = n0 + wn * 64 + ni * 16 + r;
    const float bv = bias[col];
#pragma unroll
    for (int mi = 0; mi < 4; ++mi) {
      const int rowm = m0 + wm * 64 + mi * 16 + q * 4;
      const int t = rowm >> 5;
      const int b = rowm & 31;
      const int tloc = t & (FCHUNK_T - 1);
      const bool hw = halo_on && (tloc >= FCHUNK_T - FHALO) && (t < T_DIM - FCHUNK_T);
      const size_t hbase = hw
          ? ((size_t)(((t >> 6) + 1) * FHALO + (tloc - (FCHUNK_T - FHALO))) * COLS)
          : 0;
#pragma unroll
      for (int j = 0; j < 4; ++j) {
        const float v = acc[mi][ni][j] + bv;
        Y[(size_t)(rowm + j) * DOUT + col] = v;
        if (hw) halo[hbase + (size_t)(b + j) * DOUT + col] = v;
      }
    }
  }
}

__global__ void scan_kernel(float* __restrict__ Y,
                            const float* __restrict__ halo,
                            int chunk_len)
{
  const int col4 = blockIdx.x * blockDim.x + threadIdx.x;
  const int c = blockIdx.y;

  float4* Y4 = (float4*)Y;
  const float4* H4 = (const float4*)halo;

  float4 carry = {0.0f, 0.0f, 0.0f, 0.0f};
  if (c > 0) {
#pragma unroll
    for (int h = 0; h < FHALO; ++h) {
      float4 v = H4[(size_t)(c * FHALO + h) * COLS4 + col4];
      fma4(carry, v);
    }
  }

  size_t idx = (size_t)c * chunk_len * COLS4 + col4;
  float4 ynext = Y4[idx];
  for (int t = 0; t < chunk_len; ++t) {
    float4 y = ynext;
    if (t + 1 < chunk_len) ynext = Y4[idx + COLS4];
    fma4(carry, y);
    Y4[idx] = carry;
    idx += COLS4;
  }
}

// ---------------------------------------------------------------------------
extern "C" void kernel_launch(void* const* d_in, const int* in_sizes, int n_in,
                              void* d_out, int out_size, void* d_ws, size_t ws_size,
                              hipStream_t stream)
{
  const float* X    = (const float*)d_in[0];  // [T, B, DIN]
  const float* W    = (const float*)d_in[1];  // [DOUT, DIN]
  const float* bias = (const float*)d_in[2];  // [DOUT]
  float* Y = (float*)d_out;                   // [T, B, DOUT]

  const size_t need_new = (size_t)M_DIM * DIN * 2 + (size_t)DOUT * DIN * 2; // 64.5 MiB

  if (ws_size >= need_new) {
    uint16_t* XF = (uint16_t*)d_ws;
    uint16_t* WB = XF + (size_t)M_DIM * DIN;

    wconv_kernel<<<16, 256, 0, stream>>>(W, WB);
    dim3 gf(COLS4 / FT_C4, T_DIM / FT_T);   // (64, 64)
    filter_x_kernel<<<gf, 256, 0, stream>>>(X, XF);
    gemm_bf16_kernel<<<2048, 256, 0, stream>>>(XF, WB, bias, Y);
  } else {
    float* halo = (float*)d_ws;
    const size_t halo_need = (size_t)FCHUNKS * FHALO * COLS * sizeof(float);
    const int halo_on = (ws_size >= halo_need) ? 1 : 0;

    dim3 g1(DOUT / 128, M_DIM / 128);
    gemm_bias_kernel<<<g1, 256, 0, stream>>>(X, W, bias, Y, halo, halo_on);

    const int n_chunks = halo_on ? FCHUNKS : 1;
    dim3 g2(COLS4 / 256, n_chunks);
    scan_kernel<<<g2, 256, 0, stream>>>(Y, halo, T_DIM / n_chunks);
  }
}